// Round 2
// baseline (1459.246 us; speedup 1.0000x reference)
//
#include <hip/hip_runtime.h>
#include <hip/hip_bf16.h>

// MLP 3->64->64->64->64->12, full Jacobian d(out)/d(x) per point via 3 forward
// tangents. 4 lanes per point; each lane owns a 16-neuron slice of
// {h, t0, t1, t2} in registers. Weights staged in LDS (54 KB/block).
// Cross-lane h/t broadcast via __shfl within the 4-lane group.

#define THREADS 256
#define PPB 64  // points per block (4 waves * 16 points/wave)

__device__ __forceinline__ void store12(float* ob, const float (&o)[12]) {
    float4 v0 = make_float4(o[0], o[1], o[2], o[3]);
    float4 v1 = make_float4(o[4], o[5], o[6], o[7]);
    float4 v2 = make_float4(o[8], o[9], o[10], o[11]);
    *(float4*)(ob + 0) = v0;
    *(float4*)(ob + 4) = v1;
    *(float4*)(ob + 8) = v2;
}

__global__ __launch_bounds__(THREADS, 2)
void PartialDerivatives_kernel(const float* __restrict__ x,
                               const float* __restrict__ W1, const float* __restrict__ b1,
                               const float* __restrict__ W2, const float* __restrict__ b2,
                               const float* __restrict__ W3, const float* __restrict__ b3,
                               const float* __restrict__ W4, const float* __restrict__ b4,
                               const float* __restrict__ W5,
                               float* __restrict__ out, int N)
{
    __shared__ __align__(16) float sW1[192];      // [3][64]
    __shared__ __align__(16) float sb1[64];
    __shared__ __align__(16) float sWh[3 * 4096]; // W2,W3,W4 row-major [64][64]
    __shared__ __align__(16) float sbh[3 * 64];   // b2,b3,b4
    __shared__ __align__(16) float sW5[768];      // [64][12]

    const int tid = threadIdx.x;
    for (int i = tid; i < 4096; i += THREADS) {
        sWh[i]        = W2[i];
        sWh[4096 + i] = W3[i];
        sWh[8192 + i] = W4[i];
    }
    for (int i = tid; i < 768; i += THREADS) sW5[i] = W5[i];
    for (int i = tid; i < 192; i += THREADS) sW1[i] = W1[i];
    if (tid < 64) {
        sb1[tid]       = b1[tid];
        sbh[tid]       = b2[tid];
        sbh[64 + tid]  = b3[tid];
        sbh[128 + tid] = b4[tid];
    }
    __syncthreads();

    const int lane = tid & 63;
    const int wv   = tid >> 6;
    const int jl   = lane & 3;        // lane within 4-lane point group
    const int j0   = jl * 16;         // this lane's neuron slice [j0, j0+16)
    int point = blockIdx.x * PPB + wv * 16 + (lane >> 2);
    const bool valid = point < N;
    const int pclamp = valid ? point : (N - 1);

    const float x0 = x[pclamp * 3 + 0];
    const float x1 = x[pclamp * 3 + 1];
    const float x2 = x[pclamp * 3 + 2];

    float h[16], t0[16], t1[16], t2[16];

    // ---- Layer 1: z1 = x @ W1 + b1 ; t_p = W1[p,:] * silu'(z1) ----
    #pragma unroll
    for (int j = 0; j < 16; ++j) {
        float w0 = sW1[      j0 + j];
        float w1 = sW1[ 64 + j0 + j];
        float w2 = sW1[128 + j0 + j];
        float z  = sb1[j0 + j] + x0 * w0 + x1 * w1 + x2 * w2;
        float sg = 1.f / (1.f + expf(-z));
        float d  = sg * (1.f + z * (1.f - sg));
        h[j]  = z * sg;
        t0[j] = w0 * d;
        t1[j] = w1 * d;
        t2[j] = w2 * d;
    }

    // ---- Layers 2..4: z = h @ W + b ; h' = silu(z) ; t' = (t @ W) * silu'(z) ----
    for (int l = 0; l < 3; ++l) {
        const float* Wl = &sWh[l * 4096];
        const float* bl = &sbh[l * 64];
        float hn[16], a0[16], a1[16], a2[16];
        #pragma unroll
        for (int j = 0; j < 16; ++j) {
            hn[j] = bl[j0 + j];
            a0[j] = 0.f; a1[j] = 0.f; a2[j] = 0.f;
        }
        for (int kb = 0; kb < 4; ++kb) {
            #pragma unroll
            for (int ki = 0; ki < 16; ++ki) {
                // broadcast global k = kb*16+ki (held by subgroup lane kb, elem ki)
                float hk = __shfl(h[ki],  kb, 4);
                float u0 = __shfl(t0[ki], kb, 4);
                float u1 = __shfl(t1[ki], kb, 4);
                float u2 = __shfl(t2[ki], kb, 4);
                const float* wr = &Wl[(kb * 16 + ki) * 64 + j0];
                float w[16];
                *(float4*)&w[0]  = *(const float4*)(wr + 0);
                *(float4*)&w[4]  = *(const float4*)(wr + 4);
                *(float4*)&w[8]  = *(const float4*)(wr + 8);
                *(float4*)&w[12] = *(const float4*)(wr + 12);
                #pragma unroll
                for (int j = 0; j < 16; ++j) {
                    hn[j] = fmaf(hk, w[j], hn[j]);
                    a0[j] = fmaf(u0, w[j], a0[j]);
                    a1[j] = fmaf(u1, w[j], a1[j]);
                    a2[j] = fmaf(u2, w[j], a2[j]);
                }
            }
        }
        #pragma unroll
        for (int j = 0; j < 16; ++j) {
            float z  = hn[j];
            float sg = 1.f / (1.f + expf(-z));
            float d  = sg * (1.f + z * (1.f - sg));
            h[j]  = z * sg;               // unused after l==2, harmless
            t0[j] = a0[j] * d;
            t1[j] = a1[j] * d;
            t2[j] = a2[j] * d;
        }
    }

    // ---- Output layer: jac[p][m] = sum_k t_p[k] * W5[k][m] (no silu, bias drops) ----
    float o0[12], o1[12], o2[12];
    #pragma unroll
    for (int m = 0; m < 12; ++m) { o0[m] = 0.f; o1[m] = 0.f; o2[m] = 0.f; }
    #pragma unroll
    for (int ki = 0; ki < 16; ++ki) {
        const float* wr = &sW5[(j0 + ki) * 12];
        float w[12];
        *(float4*)&w[0] = *(const float4*)(wr + 0);
        *(float4*)&w[4] = *(const float4*)(wr + 4);
        *(float4*)&w[8] = *(const float4*)(wr + 8);
        #pragma unroll
        for (int m = 0; m < 12; ++m) {
            o0[m] = fmaf(t0[ki], w[m], o0[m]);
            o1[m] = fmaf(t1[ki], w[m], o1[m]);
            o2[m] = fmaf(t2[ki], w[m], o2[m]);
        }
    }
    // butterfly reduce across the 4-lane group
    #pragma unroll
    for (int m = 0; m < 12; ++m) {
        o0[m] += __shfl_xor(o0[m], 1, 4); o0[m] += __shfl_xor(o0[m], 2, 4);
        o1[m] += __shfl_xor(o1[m], 1, 4); o1[m] += __shfl_xor(o1[m], 2, 4);
        o2[m] += __shfl_xor(o2[m], 1, 4); o2[m] += __shfl_xor(o2[m], 2, 4);
    }

    if (valid && jl < 3) {
        float* ob = out + (size_t)point * 36 + jl * 12;
        if (jl == 0)      store12(ob, o0);
        else if (jl == 1) store12(ob, o1);
        else              store12(ob, o2);
    }
}

extern "C" void kernel_launch(void* const* d_in, const int* in_sizes, int n_in,
                              void* d_out, int out_size, void* d_ws, size_t ws_size,
                              hipStream_t stream) {
    const float* x  = (const float*)d_in[0];
    const float* W1 = (const float*)d_in[1];
    const float* b1 = (const float*)d_in[2];
    const float* W2 = (const float*)d_in[3];
    const float* b2 = (const float*)d_in[4];
    const float* W3 = (const float*)d_in[5];
    const float* b3 = (const float*)d_in[6];
    const float* W4 = (const float*)d_in[7];
    const float* b4 = (const float*)d_in[8];
    const float* W5 = (const float*)d_in[9];
    // d_in[10] = b5: not needed (bias has zero Jacobian; primal output unused)
    float* out = (float*)d_out;

    const int N = in_sizes[0] / 3;
    const int blocks = (N + PPB - 1) / PPB;
    PartialDerivatives_kernel<<<blocks, THREADS, 0, stream>>>(
        x, W1, b1, W2, b2, W3, b3, W4, b4, W5, out, N);
}

// Round 3
// 648.466 us; speedup vs baseline: 2.2503x; 2.2503x over previous
//
#include <hip/hip_runtime.h>
#include <hip/hip_bf16.h>

// Jacobian of MLP 3->64->64->64->64->12 via 3 forward tangents, batched as
// 4 streams (h,t0,t1,t2) per point through bf16 MFMA (32x32x16).
//
// Layout: Z^T = W^T * H^T. MFMA N-cols = 64 point-stream rows (16 pts x 4
// streams, 2 N-tiles); M-rows = neurons (2 M-tiles). Each lane owns one
// point-stream column (c = lane&31, stream s = lane&3) -> silu'/tangent
// scaling needs only a quad-broadcast (DPP, no LDS). Next-layer B-fragments
// built in-register: v_cvt_pk_bf16_f32 + v_permlane32_swap_b32.
// Weights: hi-bf16, staged in LDS pre-permuted to fragment order (conflict-
// free ds_read_b128). Activations: split hi/lo bf16 -> 2 products per frag
// (error ~2^-17; reference's own bf16 matmul noise ~2^-8 dominates).
// Biases: exact f32 accumulator-init from LDS (zeros in this bench anyway).

#define THREADS 256

typedef float  f32x16 __attribute__((ext_vector_type(16)));
typedef float  f32x4  __attribute__((ext_vector_type(4)));
typedef short  s16x8  __attribute__((ext_vector_type(8)));

#define MFMA(a, b, c) __builtin_amdgcn_mfma_f32_32x32x16_bf16(a, b, c, 0, 0, 0)

__device__ __forceinline__ uint cvtpk(float a, float b) {
    uint r;
    asm("v_cvt_pk_bf16_f32 %0, %1, %2" : "=v"(r) : "v"(a), "v"(b));
    return r;
}
__device__ __forceinline__ void plswap(uint &a, uint &b) {
    asm("v_permlane32_swap_b32 %0, %1" : "+v"(a), "+v"(b));
}
__device__ __forceinline__ float quad0(float v) {  // broadcast quad-lane 0
    return __int_as_float(__builtin_amdgcn_mov_dpp(__float_as_int(v), 0, 0xF, 0xF, false));
}
__device__ __forceinline__ ushort bfhi(float v) {  // bf16 RNE
    uint u = __float_as_uint(v);
    return (ushort)((u + 0x7FFFu + ((u >> 16) & 1u)) >> 16);
}
__device__ __forceinline__ s16x8 mk8(uint a, uint b, uint c, uint d) {
    union { uint u[4]; s16x8 s; } x;
    x.u[0] = a; x.u[1] = b; x.u[2] = c; x.u[3] = d;
    return x.s;
}
__device__ __forceinline__ void pack_pairs(const f32x16 &A, const int i0,
                                           uint (&H)[4], uint (&L)[4]) {
    #pragma unroll
    for (int q = 0; q < 4; ++q) {
        float v0 = A[i0 + 2 * q], v1 = A[i0 + 2 * q + 1];
        uint  Hc = cvtpk(v0, v1);
        float r0 = v0 - __uint_as_float(Hc << 16);
        float r1 = v1 - __uint_as_float(Hc & 0xFFFF0000u);
        H[q] = Hc;
        L[q] = cvtpk(r0, r1);
    }
    plswap(H[0], H[2]); plswap(H[1], H[3]);
    plswap(L[0], L[2]); plswap(L[1], L[3]);
}

__global__ __launch_bounds__(THREADS, 3)
void PartialDerivatives_mfma(const float* __restrict__ x,
                             const float* __restrict__ W1, const float* __restrict__ b1,
                             const float* __restrict__ W2, const float* __restrict__ b2,
                             const float* __restrict__ W3, const float* __restrict__ b3,
                             const float* __restrict__ W4, const float* __restrict__ b4,
                             const float* __restrict__ W5,
                             float* __restrict__ out, int N, int ntiles)
{
    // Fragment-ordered weight staging: [l][mt][kk][lane][e] -> lane reads its
    // 16B A-fragment at consecutive addresses (conflict-free ds_read_b128).
    __shared__ __align__(16) ushort sWH[3 * 2 * 4 * 64 * 8]; // W2..W4^T, 24 KB
    __shared__ __align__(16) ushort sW1[2 * 64 * 8];         // W1^T (k<3), 2 KB
    __shared__ __align__(16) ushort sW5[4 * 64 * 8];         // W5^T (m<12 pad), 4 KB
    __shared__ __align__(16) float  sB[4 * 64];              // b1..b4 f32, 1 KB

    const int tid = threadIdx.x;
    for (int i = tid; i < 12288; i += THREADS) {
        int e = i & 7, lane = (i >> 3) & 63, kk = (i >> 9) & 3, mt = (i >> 11) & 1, l = i >> 12;
        int n = mt * 32 + (lane & 31);
        int k = kk * 16 + (lane >> 5) * 8 + e;
        const float* W = (l == 0) ? W2 : (l == 1) ? W3 : W4;
        sWH[i] = bfhi(W[k * 64 + n]);           // A[n][k] = W[k][n]
    }
    for (int i = tid; i < 1024; i += THREADS) {
        int e = i & 7, lane = (i >> 3) & 63, mt = i >> 9;
        int n = mt * 32 + (lane & 31);
        int k = (lane >> 5) * 8 + e;
        sW1[i] = (k < 3) ? bfhi(W1[k * 64 + n]) : (ushort)0;
    }
    for (int i = tid; i < 2048; i += THREADS) {
        int e = i & 7, lane = (i >> 3) & 63, kk = i >> 9;
        int m = lane & 31;
        int k = kk * 16 + (lane >> 5) * 8 + e;
        sW5[i] = (m < 12) ? bfhi(W5[k * 12 + m]) : (ushort)0;
    }
    if (tid < 64) {
        sB[tid] = b1[tid]; sB[64 + tid] = b2[tid];
        sB[128 + tid] = b3[tid]; sB[192 + tid] = b4[tid];
    }
    __syncthreads();

    const int  lane = tid & 63;
    const int  hi   = lane >> 5;
    const int  s    = lane & 3;          // stream: 0=h, 1..3=tangent xyz
    const bool is0  = (s == 0);
    const int  pq   = (lane & 31) >> 2;  // point within half-tile, 0..7

    const int wid = blockIdx.x * (THREADS / 64) + (tid >> 6);
    const int nw  = gridDim.x * (THREADS / 64);

    // silu epilogue: col r's scale from quad leader's z (stream 0)
#define SILU16(A)                                                              \
    { _Pragma("unroll")                                                        \
      for (int i = 0; i < 16; ++i) {                                           \
          float v  = A[i];                                                     \
          float zb = quad0(v);                                                 \
          float ez = __expf(-zb);                                              \
          float sg = __builtin_amdgcn_rcpf(1.f + ez);                          \
          float d  = __builtin_fmaf(zb * sg, 1.f - sg, sg);                    \
          A[i] = v * (is0 ? sg : d);                                           \
      } }

#define EPILOGUE()                                                             \
    {   SILU16(a00); SILU16(a01); SILU16(a10); SILU16(a11);                    \
        pack_pairs(a00, 0, Bh[0][0], Bl[0][0]);                                \
        pack_pairs(a01, 0, Bh[0][1], Bl[0][1]);                                \
        pack_pairs(a00, 8, Bh[1][0], Bl[1][0]);                                \
        pack_pairs(a01, 8, Bh[1][1], Bl[1][1]);                                \
        pack_pairs(a10, 0, Bh[2][0], Bl[2][0]);                                \
        pack_pairs(a11, 0, Bh[2][1], Bl[2][1]);                                \
        pack_pairs(a10, 8, Bh[3][0], Bl[3][0]);                                \
        pack_pairs(a11, 8, Bh[3][1], Bl[3][1]); }

#define BINIT(boff)                                                            \
    { _Pragma("unroll")                                                        \
      for (int q = 0; q < 4; ++q) {                                            \
          f32x4 bb0 = *(const f32x4*)&sB[(boff) + q * 8 + hi * 4];             \
          f32x4 bb1 = *(const f32x4*)&sB[(boff) + 32 + q * 8 + hi * 4];        \
          _Pragma("unroll")                                                    \
          for (int j = 0; j < 4; ++j) {                                        \
              a00[q * 4 + j] = bb0[j]; a01[q * 4 + j] = bb0[j];                \
              a10[q * 4 + j] = bb1[j]; a11[q * 4 + j] = bb1[j];                \
          } } }

#define HSTEP(l, kk)                                                           \
    {   s16x8 A0 = *(const s16x8*)&sWH[(((l) * 2 + 0) * 4 + (kk)) * 512 + lane * 8]; \
        s16x8 A1 = *(const s16x8*)&sWH[(((l) * 2 + 1) * 4 + (kk)) * 512 + lane * 8]; \
        s16x8 bh0 = mk8(Bh[kk][0][0], Bh[kk][0][1], Bh[kk][0][2], Bh[kk][0][3]);     \
        s16x8 bl0 = mk8(Bl[kk][0][0], Bl[kk][0][1], Bl[kk][0][2], Bl[kk][0][3]);     \
        s16x8 bh1 = mk8(Bh[kk][1][0], Bh[kk][1][1], Bh[kk][1][2], Bh[kk][1][3]);     \
        s16x8 bl1 = mk8(Bl[kk][1][0], Bl[kk][1][1], Bl[kk][1][2], Bl[kk][1][3]);     \
        a00 = MFMA(A0, bh0, a00); a00 = MFMA(A0, bl0, a00);                    \
        a01 = MFMA(A0, bh1, a01); a01 = MFMA(A0, bl1, a01);                    \
        a10 = MFMA(A1, bh0, a10); a10 = MFMA(A1, bl0, a10);                    \
        a11 = MFMA(A1, bh1, a11); a11 = MFMA(A1, bl1, a11); }

    #pragma unroll 1
    for (int t = wid; t < ntiles; t += nw) {
        const int base = t * 16;
        f32x16 a00, a01, a10, a11;
        uint Bh[4][2][4], Bl[4][2][4];

        // ---------------- Layer 1 (K=16, rows 0..2 = W1, bias via init) ----
        BINIT(0);
        {
            uint b1h[2][2] = {{0u,0u},{0u,0u}}, b1l[2][2] = {{0u,0u},{0u,0u}};
            #pragma unroll
            for (int nt = 0; nt < 2; ++nt) {
                if (hi == 0) {
                    if (is0) {
                        int pt = base + nt * 8 + pq;
                        if (pt > N - 1) pt = N - 1;
                        const float* xp = x + (size_t)pt * 3;
                        float x0 = xp[0], x1 = xp[1], x2 = xp[2];
                        uint H0 = cvtpk(x0, x1);
                        uint H1 = cvtpk(x2, 0.f);
                        float r0 = x0 - __uint_as_float(H0 << 16);
                        float r1 = x1 - __uint_as_float(H0 & 0xFFFF0000u);
                        float r2 = x2 - __uint_as_float(H1 << 16);
                        b1h[nt][0] = H0; b1h[nt][1] = H1;
                        b1l[nt][0] = cvtpk(r0, r1); b1l[nt][1] = cvtpk(r2, 0.f);
                    } else {
                        // one-hot tangent basis e_{s-1} (exact in bf16)
                        b1h[nt][0] = (s == 1) ? 0x3F80u : (s == 2) ? 0x3F800000u : 0u;
                        b1h[nt][1] = (s == 3) ? 0x3F80u : 0u;
                    }
                }
            }
            s16x8 A0 = *(const s16x8*)&sW1[0 * 512 + lane * 8];
            s16x8 A1 = *(const s16x8*)&sW1[1 * 512 + lane * 8];
            s16x8 bh0 = mk8(b1h[0][0], b1h[0][1], 0u, 0u);
            s16x8 bl0 = mk8(b1l[0][0], b1l[0][1], 0u, 0u);
            s16x8 bh1 = mk8(b1h[1][0], b1h[1][1], 0u, 0u);
            s16x8 bl1 = mk8(b1l[1][0], b1l[1][1], 0u, 0u);
            a00 = MFMA(A0, bh0, a00); a00 = MFMA(A0, bl0, a00);
            a01 = MFMA(A0, bh1, a01); a01 = MFMA(A0, bl1, a01);
            a10 = MFMA(A1, bh0, a10); a10 = MFMA(A1, bl0, a10);
            a11 = MFMA(A1, bh1, a11); a11 = MFMA(A1, bl1, a11);
        }
        EPILOGUE();

        // ---------------- Hidden layers 2..4 ------------------------------
        #pragma unroll 1
        for (int l = 0; l < 3; ++l) {
            BINIT((l + 1) * 64);
            HSTEP(l, 0); HSTEP(l, 1); HSTEP(l, 2); HSTEP(l, 3);
            EPILOGUE();
        }

        // ---------------- Output layer (M=12 padded to 32, no bias) -------
        f32x16 o0, o1;
        #pragma unroll
        for (int i = 0; i < 16; ++i) { o0[i] = 0.f; o1[i] = 0.f; }
        #pragma unroll
        for (int kk = 0; kk < 4; ++kk) {
            s16x8 A5 = *(const s16x8*)&sW5[kk * 512 + lane * 8];
            s16x8 bh0 = mk8(Bh[kk][0][0], Bh[kk][0][1], Bh[kk][0][2], Bh[kk][0][3]);
            s16x8 bl0 = mk8(Bl[kk][0][0], Bl[kk][0][1], Bl[kk][0][2], Bl[kk][0][3]);
            s16x8 bh1 = mk8(Bh[kk][1][0], Bh[kk][1][1], Bh[kk][1][2], Bh[kk][1][3]);
            s16x8 bl1 = mk8(Bl[kk][1][0], Bl[kk][1][1], Bl[kk][1][2], Bl[kk][1][3]);
            o0 = MFMA(A5, bh0, o0); o0 = MFMA(A5, bl0, o0);
            o1 = MFMA(A5, bh1, o1); o1 = MFMA(A5, bl1, o1);
        }

        // store: col r=4p+s, s>0 -> out[pt][s-1][m]; m = (i&3)+8*(i>>2)+4*hi
        if (!is0) {
            const int row = s - 1;
            #pragma unroll
            for (int nt = 0; nt < 2; ++nt) {
                int pt = base + nt * 8 + pq;
                if (pt < N) {
                    float* ob = out + (size_t)pt * 36 + row * 12;
                    const f32x16 &O = nt ? o1 : o0;
                    if (hi == 0) {
                        *(f32x4*)(ob + 0) = (f32x4){O[0], O[1], O[2], O[3]};
                        *(f32x4*)(ob + 8) = (f32x4){O[4], O[5], O[6], O[7]};
                    } else {
                        *(f32x4*)(ob + 4) = (f32x4){O[0], O[1], O[2], O[3]};
                    }
                }
            }
        }
    }
#undef SILU16
#undef EPILOGUE
#undef BINIT
#undef HSTEP
}

extern "C" void kernel_launch(void* const* d_in, const int* in_sizes, int n_in,
                              void* d_out, int out_size, void* d_ws, size_t ws_size,
                              hipStream_t stream) {
    const float* x  = (const float*)d_in[0];
    const float* W1 = (const float*)d_in[1];
    const float* b1 = (const float*)d_in[2];
    const float* W2 = (const float*)d_in[3];
    const float* b2 = (const float*)d_in[4];
    const float* W3 = (const float*)d_in[5];
    const float* b3 = (const float*)d_in[6];
    const float* W4 = (const float*)d_in[7];
    const float* b4 = (const float*)d_in[8];
    const float* W5 = (const float*)d_in[9];
    // d_in[10] = b5: unused (bias has zero Jacobian)
    float* out = (float*)d_out;

    const int N = in_sizes[0] / 3;
    const int ntiles = (N + 15) / 16;
    const int blocks = 2048;
    PartialDerivatives_mfma<<<blocks, THREADS, 0, stream>>>(
        x, W1, b1, W2, b2, W3, b3, W4, b4, W5, out, N, ntiles);
}